// Round 5
// baseline (232.451 us; speedup 1.0000x reference)
//
#include <hip/hip_runtime.h>
#include <hip/hip_bf16.h>

#define C_DIM 256
#define W_DIM 4096
#define LDS_BYTES 40656

typedef unsigned short u16;
typedef short s16x8 __attribute__((ext_vector_type(8)));
typedef unsigned short u16x8 __attribute__((ext_vector_type(8)));
typedef unsigned short u16x4 __attribute__((ext_vector_type(4)));
typedef float f32x16 __attribute__((ext_vector_type(16)));

__device__ __forceinline__ u16 f2b(float f) {
  return __builtin_bit_cast(u16, __float2bfloat16(f));
}
__device__ __forceinline__ float b2f(u16 u) {
  return __builtin_bit_cast(float, ((unsigned)u) << 16);
}

// ---------------- prep kernel (unchanged) ----------------
// ws: [0,131072) M bf16 [256][256]; [131072,262144) Wv bf16;
//     [262144) u0[256] f32; [263168) u1[256] f32; [264192) c0 f32
__global__ __launch_bounds__(256) void prep_kernel(
    const float* __restrict__ Wq, const float* __restrict__ bq,
    const float* __restrict__ Wk, const float* __restrict__ bk,
    const float* __restrict__ Wv, char* __restrict__ ws) {
  u16* Mb   = (u16*)ws;
  u16* Wvb  = (u16*)(ws + 131072);
  float* u0 = (float*)(ws + 262144);
  float* u1 = (float*)(ws + 263168);
  float* c0p = (float*)(ws + 264192);
  int bid = blockIdx.x, t = threadIdx.x;
  if (bid < 256) {
    __shared__ float Wqs[256*17];
    __shared__ float Wks[256*17];
    int i0 = (bid >> 4) << 4, j0 = (bid & 15) << 4;
    for (int it = 0; it < 16; ++it) {
      int e = t + 256*it; int a = e >> 4, ii = e & 15;
      Wqs[a*17+ii] = Wq[a*256 + i0 + ii];
      Wks[a*17+ii] = Wk[a*256 + j0 + ii];
    }
    __syncthreads();
    int ii = t >> 4, jj = t & 15;
    float acc = 0.f;
    #pragma unroll 8
    for (int a = 0; a < 256; ++a) acc += Wqs[a*17+ii] * Wks[a*17+jj];
    Mb[(i0+ii)*256 + j0 + jj] = f2b(acc);
  } else if (bid == 256) {
    int j = t;
    float a0 = 0.f, a1 = 0.f;
    #pragma unroll 4
    for (int a = 0; a < 256; ++a) {
      a0 += bq[a] * Wk[a*256 + j];
      a1 += bk[a] * Wq[a*256 + j];
    }
    u0[j] = a0; u1[j] = a1;
    __shared__ float red[256];
    red[t] = bq[t] * bk[t];
    __syncthreads();
    if (t == 0) { float s = 0.f; for (int a = 0; a < 256; ++a) s += red[a]; *c0p = s; }
  } else {
    int base = ((bid - 257)*256 + t) * 4;
    const float4 v = *reinterpret_cast<const float4*>(Wv + base);
    ushort4 pk = make_ushort4(f2b(v.x), f2b(v.y), f2b(v.z), f2b(v.w));
    *reinterpret_cast<ushort4*>(Wvb + base) = pk;
  }
}

// ---------------- main fused kernel ----------------
// 1024 blocks = (b 0..15) x (chunk 0..63 of 64 output cols). 512 thr.
// LDS 40656 B -> 4 blocks/CU:
//   Xt [kk=c>>3 0..31][j 0..65][e=c&7] bf16                      33792 B
//   Ps region (time-shared):                                      6336 B
//     phase A: PsA [2][8][66] f32 (4224) + HalA [2][2][32] (512) @f1056
//     phase B: PsB [3][8][66] f32 (6336)
//   ABs [2][66] f32                                                528 B
__global__ __launch_bounds__(512, 8) void main_kernel(
    const float* __restrict__ x, const char* __restrict__ ws,
    const float* __restrict__ bv, float* __restrict__ out) {
  const u16* Mb   = (const u16*)ws;
  const u16* Wvb  = (const u16*)(ws + 131072);
  const float* u0 = (const float*)(ws + 262144);
  const float* u1 = (const float*)(ws + 263168);
  const float c0  = *(const float*)(ws + 264192);

  extern __shared__ char lds[];
  u16* Xt    = (u16*)lds;               // 16896 u16
  float* Ps  = (float*)(lds + 33792);   // 1584 f32 (shared region)
  float* ABs = (float*)(lds + 40128);   // 132 f32

  const int bid = blockIdx.x;
  const int t = threadIdx.x;
  const int wv = t >> 6, l = t & 63;
  const int col = l & 31, half = l >> 5;

  const int b  = bid >> 6;
  const int cw = bid & 63;
  const int w0 = cw * 64;
  const float* xb = x + (size_t)b * (C_DIM*W_DIM);
  float* outb = out + (size_t)b * (C_DIM*W_DIM);

  // ---- P0: load x (32 batched), stage bf16, alpha/beta partials ----
  {
    int wg = w0 - 1 + l;
    bool ok = (wg >= 0);                         // upper bound always in-range
    const float* xp = xb + wg;
    float xr[32];
    #pragma unroll
    for (int r = 0; r < 4; ++r)
      #pragma unroll
      for (int e = 0; e < 8; ++e)
        xr[r*8+e] = ok ? xp[(size_t)((wv + 8*r)*8 + e) * W_DIM] : 0.f;

    // halo loads (cols 64,65) issued before any consumption
    const bool halo = (t < 64);
    int jh = 64 + (t & 1), kkh = t >> 1;
    int wgh = w0 - 1 + jh;
    bool okh = halo && (wgh < W_DIM);
    float he[8];
    #pragma unroll
    for (int e = 0; e < 8; ++e)
      he[e] = okh ? xb[(size_t)(kkh*8+e)*W_DIM + wgh] : 0.f;

    float pa = 0.f, pb_ = 0.f;
    #pragma unroll
    for (int r = 0; r < 4; ++r) {
      int kk = wv + 8*r;
      union { u16 u[8]; u16x8 vv; } pk;
      #pragma unroll
      for (int e = 0; e < 8; ++e) {
        float v = xr[r*8+e];
        pk.u[e] = f2b(v);
        int c = kk*8 + e;
        pa  += u0[c] * v;
        pb_ += u1[c] * v;
      }
      *reinterpret_cast<u16x8*>(Xt + (kk*66 + l)*8) = pk.vv;
    }
    Ps[wv*66 + l] = pa;
    Ps[528 + wv*66 + l] = pb_;

    if (halo) {
      float ha = 0.f, hb = 0.f;
      union { u16 u[8]; u16x8 vv; } pk;
      #pragma unroll
      for (int e = 0; e < 8; ++e) {
        pk.u[e] = f2b(he[e]);
        int c = kkh*8 + e;
        ha += u0[c] * he[e];
        hb += u1[c] * he[e];
      }
      *reinterpret_cast<u16x8*>(Xt + (kkh*66 + jh)*8) = pk.vv;
      int j2 = t & 1;
      Ps[1056 + j2*32 + kkh] = ha;          // HalA alpha
      Ps[1056 + 64 + j2*32 + kkh] = hb;     // HalA beta
    }
  }
  __syncthreads();   // bar1

  // ---- GEMM1: G = M @ X (3 n-tiles: cols 0-31, 32-63, 64-65) ----
  f32x16 acc0, acc1, acc2;
  #pragma unroll
  for (int r = 0; r < 16; ++r) { acc0[r] = 0.f; acc1[r] = 0.f; acc2[r] = 0.f; }
  {
    const u16* Arow = Mb + (32*wv + col)*256 + 8*half;
    #pragma unroll
    for (int kk = 0; kk < 16; ++kk) {
      s16x8 a = *reinterpret_cast<const s16x8*>(Arow + 16*kk);
      const u16* Bb = Xt + (2*kk + half)*66*8;
      s16x8 b0 = *reinterpret_cast<const s16x8*>(Bb + col*8);
      s16x8 b1 = *reinterpret_cast<const s16x8*>(Bb + (col+32)*8);
      s16x8 b2 = *reinterpret_cast<const s16x8*>(Bb + (col+64)*8);  // cols>=2 junk, never read
      acc0 = __builtin_amdgcn_mfma_f32_32x32x16_bf16(a, b0, acc0, 0, 0, 0);
      acc1 = __builtin_amdgcn_mfma_f32_32x32x16_bf16(a, b1, acc1, 0, 0, 0);
      acc2 = __builtin_amdgcn_mfma_f32_32x32x16_bf16(a, b2, acc2, 0, 0, 0);
    }
  }
  // ABs reduce (reads PsA/HalA written pre-bar1)
  if (t < 132) {
    int which = (t >= 66) ? 1 : 0;
    int jj = t - 66*which;
    float s = 0.f;
    if (jj < 64) {
      #pragma unroll
      for (int g = 0; g < 8; ++g) s += Ps[which*528 + g*66 + jj];
    } else {
      int j2 = jj - 64;
      #pragma unroll
      for (int g = 0; g < 32; ++g) s += Ps[1056 + which*64 + j2*32 + g];
    }
    ABs[which*66 + jj] = s;
  }
  __syncthreads();   // bar1.5: Ps region transitions PsA -> PsB

  // ---- P2: score partials from acc regs -> PsB ----
  {
    float t0s0=0.f,t0s1=0.f,t0s2=0.f,t1s0=0.f,t1s1=0.f,t1s2=0.f,t2s1=0.f,t2s2=0.f;
    const int e0 = 4*half;
    int jm0 = (col > 0) ? col-1 : 0;
    int jm2 = (63+col > 65) ? 65 : 63+col;
    int jc2 = (64+col > 65) ? 65 : 64+col;
    #pragma unroll
    for (int q = 0; q < 4; ++q) {
      const u16* base = Xt + (4*wv + q)*66*8 + e0;
      u16x4 xT0m = *reinterpret_cast<const u16x4*>(base + jm0*8);
      u16x4 xT0c = *reinterpret_cast<const u16x4*>(base + col*8);
      u16x4 xT0p = *reinterpret_cast<const u16x4*>(base + (col+1)*8);
      u16x4 xT1m = *reinterpret_cast<const u16x4*>(base + (col+31)*8);
      u16x4 xT1c = *reinterpret_cast<const u16x4*>(base + (col+32)*8);
      u16x4 xT1p = *reinterpret_cast<const u16x4*>(base + (col+33)*8);
      u16x4 xT2m = *reinterpret_cast<const u16x4*>(base + jm2*8);
      u16x4 xT2c = *reinterpret_cast<const u16x4*>(base + jc2*8);
      #pragma unroll
      for (int r4 = 0; r4 < 4; ++r4) {
        float g0 = acc0[4*q+r4], g1 = acc1[4*q+r4], g2 = acc2[4*q+r4];
        t0s1 += g0 * b2f(xT0c[r4]);
        t0s0 += g0 * b2f(xT0p[r4]);
        t0s2 += g0 * b2f(xT0m[r4]);
        t1s1 += g1 * b2f(xT1c[r4]);
        t1s0 += g1 * b2f(xT1p[r4]);
        t1s2 += g1 * b2f(xT1m[r4]);
        t2s1 += g2 * b2f(xT2c[r4]);
        t2s2 += g2 * b2f(xT2m[r4]);
      }
    }
    t0s0 += __shfl_xor(t0s0, 32); t0s1 += __shfl_xor(t0s1, 32);
    t0s2 += __shfl_xor(t0s2, 32); t1s0 += __shfl_xor(t1s0, 32);
    t1s1 += __shfl_xor(t1s1, 32); t1s2 += __shfl_xor(t1s2, 32);
    t2s1 += __shfl_xor(t2s1, 32); t2s2 += __shfl_xor(t2s2, 32);
    float* PBw = Ps + wv*66;
    if (half == 0) {
      PBw[0*528 + col+1]  = t0s0;
      PBw[1*528 + col]    = t0s1;
      if (col >= 1) PBw[2*528 + col-1] = t0s2;
      PBw[0*528 + col+33] = t1s0;
      PBw[1*528 + col+32] = t1s1;
      PBw[2*528 + col+31] = t1s2;
    } else if (col < 2) {
      PBw[1*528 + col+64] = t2s1;
      PBw[2*528 + col+63] = t2s2;
    }
  }
  __syncthreads();   // bar2

  // ---- P3: softmax (output col j=l+1, w=w0+l) + in-place mix in Xt ----
  {
    float d0 = 0.f, d1 = 0.f, d2 = 0.f;
    #pragma unroll
    for (int g = 0; g < 8; ++g) {
      d0 += Ps[0*528 + g*66 + l+1];
      d1 += Ps[1*528 + g*66 + l+1];
      d2 += Ps[2*528 + g*66 + l+1];
    }
    float am = ABs[l], ac = ABs[l+1], ap = ABs[l+2];
    float be = ABs[66 + l+1];
    float sc0 = (d0 + am + be + c0) * 0.0625f;
    float sc1 = (d1 + ac + be + c0) * 0.0625f;
    float sc2 = (d2 + ap + be + c0) * 0.0625f;
    int w = w0 + l;
    bool v0 = (w >= 1), v2 = (w + 1 < W_DIM);
    const float NEG = -1e30f;
    float m = fmaxf(v0 ? sc0 : NEG, fmaxf(sc1, v2 ? sc2 : NEG));
    float e0v = v0 ? __expf(sc0 - m) : 0.f;
    float e1v = __expf(sc1 - m);
    float e2v = v2 ? __expf(sc2 - m) : 0.f;
    float inv = 1.f / (e0v + e1v + e2v);
    float a0 = e0v*inv, a1 = e1v*inv, a2 = e2v*inv;
    #pragma unroll
    for (int kg = 0; kg < 4; ++kg) {
      int kk = 4*wv + kg;
      u16* base = Xt + kk*66*8;
      u16x8 xm  = *reinterpret_cast<const u16x8*>(base + l*8);
      u16x8 xc_ = *reinterpret_cast<const u16x8*>(base + (l+1)*8);
      u16x8 xp  = *reinterpret_cast<const u16x8*>(base + (l+2)*8);
      union { u16 u[8]; u16x8 vv; } pk;
      #pragma unroll
      for (int e = 0; e < 8; ++e)
        pk.u[e] = f2b(a0*b2f(xm[e]) + a1*b2f(xc_[e]) + a2*b2f(xp[e]));
      *reinterpret_cast<u16x8*>(base + (l+1)*8) = pk.vv;
    }
  }
  __syncthreads();   // bar3

  // ---- GEMM2: out = Wv @ Xmix + bv (dense aligned stores) ----
  {
    #pragma unroll
    for (int r = 0; r < 16; ++r) { acc0[r] = 0.f; acc1[r] = 0.f; }
    const u16* Arow2 = Wvb + (32*wv + col)*256 + 8*half;
    #pragma unroll
    for (int kk = 0; kk < 16; ++kk) {
      s16x8 a = *reinterpret_cast<const s16x8*>(Arow2 + 16*kk);
      const u16* Bb = Xt + (2*kk + half)*66*8;
      s16x8 b0 = *reinterpret_cast<const s16x8*>(Bb + (1+col)*8);
      s16x8 b1 = *reinterpret_cast<const s16x8*>(Bb + (33+col)*8);
      acc0 = __builtin_amdgcn_mfma_f32_32x32x16_bf16(a, b0, acc0, 0, 0, 0);
      acc1 = __builtin_amdgcn_mfma_f32_32x32x16_bf16(a, b1, acc1, 0, 0, 0);
    }
    float bvr[16];
    #pragma unroll
    for (int q = 0; q < 4; ++q) {
      float4 t4 = *reinterpret_cast<const float4*>(bv + 32*wv + 8*q + 4*half);
      bvr[4*q+0] = t4.x; bvr[4*q+1] = t4.y; bvr[4*q+2] = t4.z; bvr[4*q+3] = t4.w;
    }
    #pragma unroll
    for (int r = 0; r < 16; ++r) {
      int crow = 32*wv + (r&3) + 8*(r>>2) + 4*half;
      outb[(size_t)crow*W_DIM + w0 + col]      = acc0[r] + bvr[r];
      outb[(size_t)crow*W_DIM + w0 + 32 + col] = acc1[r] + bvr[r];
    }
  }
}

extern "C" void kernel_launch(void* const* d_in, const int* in_sizes, int n_in,
                              void* d_out, int out_size, void* d_ws, size_t ws_size,
                              hipStream_t stream) {
  (void)in_sizes; (void)n_in; (void)out_size; (void)ws_size;
  const float* x  = (const float*)d_in[0];
  const float* Wq = (const float*)d_in[1];
  const float* bq = (const float*)d_in[2];
  const float* Wk = (const float*)d_in[3];
  const float* bk = (const float*)d_in[4];
  const float* Wv = (const float*)d_in[5];
  const float* bv = (const float*)d_in[6];
  float* out = (float*)d_out;
  char* ws = (char*)d_ws;   // needs 264196 B

  hipFuncSetAttribute((const void*)main_kernel,
                      hipFuncAttributeMaxDynamicSharedMemorySize, LDS_BYTES);
  prep_kernel<<<321, 256, 0, stream>>>(Wq, bq, Wk, bk, Wv, ws);
  main_kernel<<<1024, 512, LDS_BYTES, stream>>>(x, ws, bv, out);
}

// Round 6
// 89.992 us; speedup vs baseline: 2.5830x; 2.5830x over previous
//
#include <hip/hip_runtime.h>
#include <hip/hip_bf16.h>

#define C_DIM 256
#define W_DIM 4096
#define WI 62
#define NCH 67           // ceil(4096/62)
#define LDS_BYTES 39424

typedef unsigned short u16;
typedef short s16x8 __attribute__((ext_vector_type(8)));
typedef unsigned short u16x8 __attribute__((ext_vector_type(8)));
typedef unsigned short u16x4 __attribute__((ext_vector_type(4)));
typedef float f32x16 __attribute__((ext_vector_type(16)));

__device__ __forceinline__ u16 f2b(float f) {
  return __builtin_bit_cast(u16, __float2bfloat16(f));
}
__device__ __forceinline__ float b2f(u16 u) {
  return __builtin_bit_cast(float, ((unsigned)u) << 16);
}

// ---------------- prep kernel (unchanged) ----------------
// ws: [0,131072) M bf16 [256][256]; [131072,262144) Wv bf16;
//     [262144) u0[256] f32; [263168) u1[256] f32; [264192) c0 f32
__global__ __launch_bounds__(256) void prep_kernel(
    const float* __restrict__ Wq, const float* __restrict__ bq,
    const float* __restrict__ Wk, const float* __restrict__ bk,
    const float* __restrict__ Wv, char* __restrict__ ws) {
  u16* Mb   = (u16*)ws;
  u16* Wvb  = (u16*)(ws + 131072);
  float* u0 = (float*)(ws + 262144);
  float* u1 = (float*)(ws + 263168);
  float* c0p = (float*)(ws + 264192);
  int bid = blockIdx.x, t = threadIdx.x;
  if (bid < 256) {
    __shared__ float Wqs[256*17];
    __shared__ float Wks[256*17];
    int i0 = (bid >> 4) << 4, j0 = (bid & 15) << 4;
    for (int it = 0; it < 16; ++it) {
      int e = t + 256*it; int a = e >> 4, ii = e & 15;
      Wqs[a*17+ii] = Wq[a*256 + i0 + ii];
      Wks[a*17+ii] = Wk[a*256 + j0 + ii];
    }
    __syncthreads();
    int ii = t >> 4, jj = t & 15;
    float acc = 0.f;
    #pragma unroll 8
    for (int a = 0; a < 256; ++a) acc += Wqs[a*17+ii] * Wks[a*17+jj];
    Mb[(i0+ii)*256 + j0 + jj] = f2b(acc);
  } else if (bid == 256) {
    int j = t;
    float a0 = 0.f, a1 = 0.f;
    #pragma unroll 4
    for (int a = 0; a < 256; ++a) {
      a0 += bq[a] * Wk[a*256 + j];
      a1 += bk[a] * Wq[a*256 + j];
    }
    u0[j] = a0; u1[j] = a1;
    __shared__ float red[256];
    red[t] = bq[t] * bk[t];
    __syncthreads();
    if (t == 0) { float s = 0.f; for (int a = 0; a < 256; ++a) s += red[a]; *c0p = s; }
  } else {
    int base = ((bid - 257)*256 + t) * 4;
    const float4 v = *reinterpret_cast<const float4*>(Wv + base);
    ushort4 pk = make_ushort4(f2b(v.x), f2b(v.y), f2b(v.z), f2b(v.w));
    *reinterpret_cast<ushort4*>(Wvb + base) = pk;
  }
}

// ---------------- main fused kernel ----------------
// 16*67 blocks; chunk = 62 output cols (w = w0..w0+61), G cols j=0..63, no halo tile.
// LDS 39424 B -> 3 blocks/CU (regs <= 85 via launch_bounds(512,6)):
//   Xt [kk=c>>3 0..31][j 0..63][e=c&7] bf16     32768 B
//   Ps (time-shared)                             6144 B
//     phase A: PsA [2][8][64] f32 (4096)
//     phase B: PsB [3][8][64] f32 (6144)
//   ABs [2][64] f32                               512 B
__global__ __launch_bounds__(512, 6) void main_kernel(
    const float* __restrict__ x, const char* __restrict__ ws,
    const float* __restrict__ bv, float* __restrict__ out) {
  const u16* Mb   = (const u16*)ws;
  const u16* Wvb  = (const u16*)(ws + 131072);
  const float* u0 = (const float*)(ws + 262144);
  const float* u1 = (const float*)(ws + 263168);
  const float c0  = *(const float*)(ws + 264192);

  extern __shared__ char lds[];
  u16* Xt    = (u16*)lds;               // 16384 u16
  float* Ps  = (float*)(lds + 32768);   // 1536 f32 (time-shared)
  float* ABs = (float*)(lds + 38912);   // 128 f32

  const int bid = blockIdx.x;
  const int t = threadIdx.x;
  const int wv = t >> 6, l = t & 63;
  const int col = l & 31, half = l >> 5;

  const int b  = bid / NCH;
  const int cw = bid % NCH;
  const int w0 = cw * WI;
  const float* xb = x + (size_t)b * (C_DIM*W_DIM);
  float* outb = out + (size_t)b * (C_DIM*W_DIM);

  // ---- P0: load x (32 batched), stage bf16, alpha/beta partials ----
  {
    int wg = w0 - 1 + l;                 // G col j = l
    bool ok = (wg >= 0) && (wg < W_DIM);
    const float* xp = xb + wg;
    float xr[32];
    #pragma unroll
    for (int r = 0; r < 4; ++r)
      #pragma unroll
      for (int e = 0; e < 8; ++e)
        xr[r*8+e] = ok ? xp[(size_t)((wv + 8*r)*8 + e) * W_DIM] : 0.f;

    float pa = 0.f, pb_ = 0.f;
    #pragma unroll
    for (int r = 0; r < 4; ++r) {
      int kk = wv + 8*r;
      union { u16 u[8]; u16x8 vv; } pk;
      #pragma unroll
      for (int e = 0; e < 8; ++e) {
        float v = xr[r*8+e];
        pk.u[e] = f2b(v);
        int c = kk*8 + e;
        pa  += u0[c] * v;
        pb_ += u1[c] * v;
      }
      *reinterpret_cast<u16x8*>(Xt + (kk*64 + l)*8) = pk.vv;
    }
    Ps[wv*64 + l] = pa;
    Ps[512 + wv*64 + l] = pb_;
  }
  __syncthreads();   // bar1

  // ---- GEMM1: G = M @ X (2 n-tiles: cols 0-31, 32-63) ----
  f32x16 acc0, acc1;
  #pragma unroll
  for (int r = 0; r < 16; ++r) { acc0[r] = 0.f; acc1[r] = 0.f; }
  {
    const u16* Arow = Mb + (32*wv + col)*256 + 8*half;
    #pragma unroll
    for (int kk = 0; kk < 16; ++kk) {
      s16x8 a = *reinterpret_cast<const s16x8*>(Arow + 16*kk);
      const u16* Bb = Xt + (2*kk + half)*64*8;
      s16x8 b0 = *reinterpret_cast<const s16x8*>(Bb + col*8);
      s16x8 b1 = *reinterpret_cast<const s16x8*>(Bb + (col+32)*8);
      acc0 = __builtin_amdgcn_mfma_f32_32x32x16_bf16(a, b0, acc0, 0, 0, 0);
      acc1 = __builtin_amdgcn_mfma_f32_32x32x16_bf16(a, b1, acc1, 0, 0, 0);
    }
  }
  // alpha/beta reduce (reads PsA written pre-bar1)
  if (t < 128) {
    int which = t >> 6, jj = t & 63;
    float s = 0.f;
    #pragma unroll
    for (int g = 0; g < 8; ++g) s += Ps[which*512 + g*64 + jj];
    ABs[which*64 + jj] = s;
  }
  __syncthreads();   // bar1.5: Ps transitions PsA -> PsB

  // ---- P2: score partials from acc regs -> PsB ----
  // G col j feeds: s1[j] (x_j), s0[j+1] (x_{j+1}), s2[j-1] (x_{j-1})
  {
    float t0s0=0.f,t0s1=0.f,t0s2=0.f,t1s0=0.f,t1s1=0.f,t1s2=0.f;
    const int e0 = 4*half;
    int jm0 = (col > 0) ? col-1 : 0;
    int jp1 = (col < 31) ? col+33 : 63;      // clamped; write guarded off
    #pragma unroll
    for (int q = 0; q < 4; ++q) {
      const u16* base = Xt + (4*wv + q)*64*8 + e0;
      u16x4 xT0m = *reinterpret_cast<const u16x4*>(base + jm0*8);
      u16x4 xT0c = *reinterpret_cast<const u16x4*>(base + col*8);
      u16x4 xT0p = *reinterpret_cast<const u16x4*>(base + (col+1)*8);
      u16x4 xT1m = *reinterpret_cast<const u16x4*>(base + (col+31)*8);
      u16x4 xT1c = *reinterpret_cast<const u16x4*>(base + (col+32)*8);
      u16x4 xT1p = *reinterpret_cast<const u16x4*>(base + jp1*8);
      #pragma unroll
      for (int r4 = 0; r4 < 4; ++r4) {
        float g0 = acc0[4*q+r4], g1 = acc1[4*q+r4];
        t0s1 += g0 * b2f(xT0c[r4]);
        t0s0 += g0 * b2f(xT0p[r4]);
        t0s2 += g0 * b2f(xT0m[r4]);
        t1s1 += g1 * b2f(xT1c[r4]);
        t1s0 += g1 * b2f(xT1p[r4]);
        t1s2 += g1 * b2f(xT1m[r4]);
      }
    }
    t0s0 += __shfl_xor(t0s0, 32); t0s1 += __shfl_xor(t0s1, 32);
    t0s2 += __shfl_xor(t0s2, 32); t1s0 += __shfl_xor(t1s0, 32);
    t1s1 += __shfl_xor(t1s1, 32); t1s2 += __shfl_xor(t1s2, 32);
    float* PBw = Ps + wv*64;
    if (half == 0) {
      PBw[0*512 + col+1]  = t0s0;
      PBw[1*512 + col]    = t0s1;
      if (col >= 1) PBw[2*512 + col-1] = t0s2;
      if (col < 31) PBw[0*512 + col+33] = t1s0;
      PBw[1*512 + col+32] = t1s1;
      PBw[2*512 + col+31] = t1s2;
    }
  }
  __syncthreads();   // bar2

  // ---- P3: softmax (output j=l+1, w=w0+l) + in-place mix in Xt ----
  {
    int lp2 = (l < 62) ? l+2 : 63;       // clamp: lanes l>=62 produce no output
    float d0 = 0.f, d1 = 0.f, d2 = 0.f;
    #pragma unroll
    for (int g = 0; g < 8; ++g) {
      d0 += Ps[0*512 + g*64 + l+1 - ((l==63)?1:0)];
      d1 += Ps[1*512 + g*64 + l+1 - ((l==63)?1:0)];
      d2 += Ps[2*512 + g*64 + ((l>=62)?62:l+1)];
    }
    float am = ABs[l], ac = ABs[(l<63)?l+1:63], ap = ABs[lp2];
    float be = ABs[64 + ((l<63)?l+1:63)];
    float sc0 = (d0 + am + be + c0) * 0.0625f;
    float sc1 = (d1 + ac + be + c0) * 0.0625f;
    float sc2 = (d2 + ap + be + c0) * 0.0625f;
    int w = w0 + l;
    bool v0 = (w >= 1), v2 = (w + 1 < W_DIM);
    const float NEG = -1e30f;
    float m = fmaxf(v0 ? sc0 : NEG, fmaxf(sc1, v2 ? sc2 : NEG));
    float e0v = v0 ? __expf(sc0 - m) : 0.f;
    float e1v = __expf(sc1 - m);
    float e2v = v2 ? __expf(sc2 - m) : 0.f;
    float inv = 1.f / (e0v + e1v + e2v);
    float a0 = e0v*inv, a1 = e1v*inv, a2 = e2v*inv;
    const bool wr = (l <= 61);
    #pragma unroll
    for (int kg = 0; kg < 4; ++kg) {
      int kk = 4*wv + kg;
      u16* base = Xt + kk*64*8;
      u16x8 xm  = *reinterpret_cast<const u16x8*>(base + l*8);
      u16x8 xc_ = *reinterpret_cast<const u16x8*>(base + ((l<63)?l+1:63)*8);
      u16x8 xp  = *reinterpret_cast<const u16x8*>(base + lp2*8);
      union { u16 u[8]; u16x8 vv; } pk;
      #pragma unroll
      for (int e = 0; e < 8; ++e)
        pk.u[e] = f2b(a0*b2f(xm[e]) + a1*b2f(xc_[e]) + a2*b2f(xp[e]));
      if (wr) *reinterpret_cast<u16x8*>(base + (l+1)*8) = pk.vv;
    }
  }
  __syncthreads();   // bar3

  // ---- GEMM2: out = Wv @ Xmix + bv ----
  {
    #pragma unroll
    for (int r = 0; r < 16; ++r) { acc0[r] = 0.f; acc1[r] = 0.f; }
    const u16* Arow2 = Wvb + (32*wv + col)*256 + 8*half;
    #pragma unroll
    for (int kk = 0; kk < 16; ++kk) {
      s16x8 a = *reinterpret_cast<const s16x8*>(Arow2 + 16*kk);
      const u16* Bb = Xt + (2*kk + half)*64*8;
      s16x8 b0 = *reinterpret_cast<const s16x8*>(Bb + (1+col)*8);
      // j = 33+col; col=31 reads row-local junk (clamped), stores guarded
      s16x8 b1 = *reinterpret_cast<const s16x8*>(Bb + (((col<31)?(33+col):63))*8);
      acc0 = __builtin_amdgcn_mfma_f32_32x32x16_bf16(a, b0, acc0, 0, 0, 0);
      acc1 = __builtin_amdgcn_mfma_f32_32x32x16_bf16(a, b1, acc1, 0, 0, 0);
    }
    float bvr[16];
    #pragma unroll
    for (int q = 0; q < 4; ++q) {
      float4 t4 = *reinterpret_cast<const float4*>(bv + 32*wv + 8*q + 4*half);
      bvr[4*q+0] = t4.x; bvr[4*q+1] = t4.y; bvr[4*q+2] = t4.z; bvr[4*q+3] = t4.w;
    }
    int wg0 = w0 + col;          // j = 1+col
    int wg1 = w0 + 32 + col;     // j = 33+col, valid iff col<=29
    bool st0 = (wg0 < W_DIM);
    bool st1 = (col <= 29) && (wg1 < W_DIM);
    #pragma unroll
    for (int r = 0; r < 16; ++r) {
      int crow = 32*wv + (r&3) + 8*(r>>2) + 4*half;
      if (st0) outb[(size_t)crow*W_DIM + wg0] = acc0[r] + bvr[r];
      if (st1) outb[(size_t)crow*W_DIM + wg1] = acc1[r] + bvr[r];
    }
  }
}

extern "C" void kernel_launch(void* const* d_in, const int* in_sizes, int n_in,
                              void* d_out, int out_size, void* d_ws, size_t ws_size,
                              hipStream_t stream) {
  (void)in_sizes; (void)n_in; (void)out_size; (void)ws_size;
  const float* x  = (const float*)d_in[0];
  const float* Wq = (const float*)d_in[1];
  const float* bq = (const float*)d_in[2];
  const float* Wk = (const float*)d_in[3];
  const float* bk = (const float*)d_in[4];
  const float* Wv = (const float*)d_in[5];
  const float* bv = (const float*)d_in[6];
  float* out = (float*)d_out;
  char* ws = (char*)d_ws;   // needs 264196 B

  hipFuncSetAttribute((const void*)main_kernel,
                      hipFuncAttributeMaxDynamicSharedMemorySize, LDS_BYTES);
  prep_kernel<<<321, 256, 0, stream>>>(Wq, bq, Wk, bk, Wv, ws);
  main_kernel<<<16 * NCH, 512, LDS_BYTES, stream>>>(x, ws, bv, out);
}